// Round 18
// baseline (193.385 us; speedup 1.0000x reference)
//
#include <hip/hip_runtime.h>
#include <math.h>

// ---------------------------------------------------------------------------
// MambaAnglePredictor — Round 18 (R17 +):
//   xs single bf16 (xs_l deleted); phase1 all-single (6 MFMAs, was 18);
//   phase3 intra/carry single-term (6+6 MFMAs, was 12+12; GM stays 3-term);
//   k_final merged into mlp2 (last-block ticket).
// ---------------------------------------------------------------------------

#define BDIM 4
#define LDIM 4096
#define BL (BDIM*LDIM)      // 16384 tokens
#define QC 64
#define NC (LDIM/QC)        // 64
#define BH (BDIM*NH)        // 32
#define NH 8

// workspace offsets (floats)
#define OFF_W    0u          // Weff 4x904 @0, beff @4096, Weff2 @8192
#define OFF_Z    3145728u    // ssum fp32 [16384]
#define OFF_T    9437184u    // T bf16 [p][n] per chunk
#define OFF_XS   17825792u   // xs single bf16
#define OFF_BM   24117248u   // Bm_h | Bm_l
#define OFF_CM   25165824u   // Cm_h | Cm_l
#define OFF_DT   26214400u   // 32*4096 fp32
#define OFF_LAC  26345472u   // 2048*64 fp32
#define OFF_SP   26476544u   // Sp bf16 [p][n] per chunk
#define OFF_Y    32768000u   // g bf16 (gated y, pre-RMS)
#define OFF_MACC 39059456u   // 4*32 fp32, then counter @+128

typedef unsigned short ushort_t;
typedef __attribute__((ext_vector_type(8))) short bf16x8;
typedef __attribute__((ext_vector_type(4))) float f32x4;

__device__ __forceinline__ float sigmoidf_(float x){ return 1.0f/(1.0f+__expf(-x)); }
__device__ __forceinline__ ushort_t f2bf(float x){
  unsigned int u = __float_as_uint(x);
  u += 0x7fffu + ((u>>16)&1u);
  return (ushort_t)(u>>16);
}
__device__ __forceinline__ float bf2f(ushort_t h){
  return __uint_as_float(((unsigned int)h)<<16);
}

// ----- prep: Weff, beff, Weff2 (nw-folded), macc/ssum/counter zero -----
__global__ void k_prep(const float* __restrict__ Wfc, const float* __restrict__ bfc,
                       const float* __restrict__ W_in, const float* __restrict__ W_out,
                       const float* __restrict__ W1, const float* __restrict__ norm_w,
                       float* __restrict__ Weff, float* __restrict__ beff,
                       float* __restrict__ Weff2, float* __restrict__ macc,
                       float* __restrict__ ssum, unsigned int* __restrict__ cnt){
  int blk = blockIdx.x, tid = threadIdx.x;
  if (blk < 4){
    int n = blk*256 + tid;
    if (n >= 904) return;
    float a0=0.f,a1=0.f,a2=0.f,a3=0.f,ab=0.f;
    for (int d=0; d<192; d++){
      float w = W_in[(size_t)d*904 + n];
      a0 = fmaf(Wfc[d], w, a0);
      a1 = fmaf(Wfc[192+d], w, a1);
      a2 = fmaf(Wfc[384+d], w, a2);
      a3 = fmaf(Wfc[576+d], w, a3);
      ab = fmaf(bfc[d], w, ab);
    }
    Weff[n] = a0; Weff[904+n] = a1; Weff[1808+n] = a2; Weff[2712+n] = a3;
    beff[n] = ab;
  } else if (blk < 52){
    if (blk == 4 && tid < 128) macc[tid] = 0.f;
    if (blk == 5 && tid == 0) *cnt = 0u;
    int g = (blk-4)*256 + tid;
    int i = g>>5, j = g&31;
    float a = 0.f;
    for (int d=0; d<192; d++) a = fmaf(W_out[(size_t)i*192+d], W1[d*32+j], a);
    Weff2[g] = a * norm_w[i];
  } else {
    int idx = (blk-52)*256 + tid;       // 64 blocks * 256 = 16384
    ssum[idx] = 0.f;
  }
}

// ----- ipc: fused in_proj+conv+silu+dt; 4 tokens/block; xs single bf16 -----
__global__ __launch_bounds__(256) void k_ipc(
    const float* __restrict__ x, const float* __restrict__ Weff,
    const float* __restrict__ beff, const float* __restrict__ conv_w,
    const float* __restrict__ conv_b, const float* __restrict__ dt_bias,
    ushort_t* __restrict__ xs,
    ushort_t* __restrict__ Bm_h, ushort_t* __restrict__ Bm_l,
    ushort_t* __restrict__ Cm_h, ushort_t* __restrict__ Cm_l,
    float* __restrict__ dtb){
  __shared__ float sx[7][4];            // x rows l0-3 .. l0+3
  int pb = blockIdx.x, tid = threadIdx.x;
  int bl0 = pb*4;
  int l0 = bl0 & 4095, b = bl0 >> 12;
  if (tid < 28){
    int row = tid>>2, r = tid&3;
    int ll = l0-3+row;
    sx[row][r] = (ll>=0) ? x[(size_t)(b*4096+ll)*4 + r] : 0.f;
  }
  __syncthreads();
  if (tid < 32){
    int t = tid>>3, hh = tid&7;
    float raw = beff[896+hh];
    #pragma unroll
    for (int r=0;r<4;r++) raw = fmaf(sx[3+t][r], Weff[r*904+896+hh], raw);
    float xx = raw + dt_bias[hh];
    float dtv = (xx > 20.f) ? xx : log1pf(__expf(xx));
    dtb[(size_t)(b*8+hh)*4096 + l0 + t] = dtv;
  }
  #pragma unroll
  for (int half=0; half<2; half++){
    int c = tid + half*256;
    float w0 = Weff[384+c];
    float w1 = Weff[904+384+c];
    float w2 = Weff[1808+384+c];
    float w3 = Weff[2712+384+c];
    float bb = beff[384+c];
    float cw0 = conv_w[c], cw1 = conv_w[512+c], cw2 = conv_w[1024+c], cw3 = conv_w[1536+c];
    float cb = conv_b[c];
    float pre[7];
    #pragma unroll
    for (int q=0;q<7;q++){
      int ll = l0-3+q;
      float xv = bb;
      xv = fmaf(sx[q][0], w0, xv);
      xv = fmaf(sx[q][1], w1, xv);
      xv = fmaf(sx[q][2], w2, xv);
      xv = fmaf(sx[q][3], w3, xv);
      pre[q] = (ll >= 0) ? xv : 0.f;
    }
    float av[4];
    #pragma unroll
    for (int t=0;t<4;t++){
      float a = cb;
      a = fmaf(cw0,pre[t+0],a); a = fmaf(cw1,pre[t+1],a);
      a = fmaf(cw2,pre[t+2],a); a = fmaf(cw3,pre[t+3],a);
      av[t] = a * sigmoidf_(a);
    }
    if (c < 384){
      int hh = c / 48, p = c - hh*48;
      size_t idx = (size_t)((b*8+hh)*4096 + l0)*48 + p;
      #pragma unroll
      for (int t=0;t<4;t++) xs[idx + t*48] = f2bf(av[t]);
    } else if (c < 448){
      size_t idx = (size_t)bl0*64 + (c-384);
      #pragma unroll
      for (int t=0;t<4;t++){
        ushort_t h = f2bf(av[t]);
        Bm_h[idx + t*64] = h;
        Bm_l[idx + t*64] = f2bf(av[t] - bf2f(h));
      }
    } else {
      size_t idx = (size_t)bl0*64 + (c-448);
      #pragma unroll
      for (int t=0;t<4;t++){
        ushort_t h = f2bf(av[t]);
        Cm_h[idx + t*64] = h;
        Cm_l[idx + t*64] = f2bf(av[t] - bf2f(h));
      }
    }
  }
}

// ----- phase1 (MFMA, all-single): T^T[p][n] = X^T · Bw; 6 MFMAs -----
__global__ __launch_bounds__(256, 3) void k_phase1(
    const float* __restrict__ dtbuf,
    const ushort_t* __restrict__ Bm_h,
    const ushort_t* __restrict__ xs,
    const float* __restrict__ A_log,
    ushort_t* __restrict__ T, float* __restrict__ lac){
  __shared__ __align__(16) ushort_t sBs[64*72];   // Bw^T [n][s] single
  __shared__ __align__(16) ushort_t sXs[48*72];   // X^T [p][s] single
  __shared__ float sdt[64], sla[64], sw[64];
  int tid = threadIdx.x, blk = blockIdx.x;
  int bh = blk >> 6, k = blk & 63;
  int b = bh >> 3, hh = bh & 7;
  int t0 = k*64;
  int w = tid>>6, lane = tid&63, l15 = lane&15, quad = lane>>4;

  if (tid < 64) sdt[tid] = dtbuf[(size_t)bh*4096 + t0 + tid];
  __syncthreads();
  if (tid == 0){
    float eA = __expf(A_log[hh]);
    float cum = 0.f;
    for (int i=0;i<64;i++){ cum -= sdt[i]*eA; sla[i] = cum; }
  }
  __syncthreads();
  if (tid < 64){
    sw[tid] = __expf(sla[63]-sla[tid])*sdt[tid];
    lac[(size_t)blk*64 + tid] = sla[tid];
  }
  __syncthreads();
  // ---- stage Bw^T [n][s]: B single, scale by sw, round once ----
  {
    int s2 = (tid&31)*2, ng = (tid>>5)*8;
    size_t base0 = (size_t)(b*4096+t0+s2)*64 + ng;
    ushort_t h0a[8], h1a[8];
    *(uint4*)h0a = *(const uint4*)(Bm_h + base0);
    *(uint4*)h1a = *(const uint4*)(Bm_h + base0 + 64);
    float w0 = sw[s2], w1 = sw[s2+1];
    #pragma unroll
    for (int c=0;c<8;c++){
      ushort_t h0 = f2bf(bf2f(h0a[c]) * w0);
      ushort_t h1 = f2bf(bf2f(h1a[c]) * w1);
      *(unsigned int*)&sBs[(ng+c)*72 + s2] = (unsigned int)h0 | ((unsigned int)h1<<16);
    }
  }
  // ---- stage X^T [p][s]: pure copy + pack ----
  {
    int s2 = (tid>>3)*2, p0 = (tid&7)*6;
    const ushort_t* xh0 = xs + (size_t)(bh*4096+t0+s2)*48 + p0;
    #pragma unroll
    for (int c=0;c<6;c++){
      unsigned int hv = (unsigned int)xh0[c] | ((unsigned int)xh0[48+c]<<16);
      *(unsigned int*)&sXs[(p0+c)*72 + s2] = hv;
    }
  }
  __syncthreads();
  f32x4 acc[3];
  #pragma unroll
  for (int t=0;t<3;t++) acc[t] = (f32x4)(0.f);
  #pragma unroll
  for (int ks=0;ks<2;ks++){
    int bo = (w*16+l15)*72 + ks*32 + quad*8;
    bf16x8 bbs = *(bf16x8*)&sBs[bo];
    #pragma unroll
    for (int pt=0;pt<3;pt++){
      int xo = (pt*16+l15)*72 + ks*32 + quad*8;
      bf16x8 xas = *(bf16x8*)&sXs[xo];
      acc[pt] = __builtin_amdgcn_mfma_f32_16x16x32_bf16(xas, bbs, acc[pt], 0,0,0);
    }
  }
  {
    ushort_t* dst = T + (size_t)blk*3072;
    #pragma unroll
    for (int pt=0;pt<3;pt++)
      #pragma unroll
      for (int r=0;r<4;r++)
        dst[(pt*16+quad*4+r)*64 + w*16 + l15] = f2bf(acc[pt][r]);
  }
}

// ----- phase2p: Sp[k] = sum_{j<k} W[k][j] T[j]; T bf16 in, Sp bf16 out -----
__global__ __launch_bounds__(256) void k_phase2p(
    const ushort_t* __restrict__ T, const float* __restrict__ lac,
    ushort_t* __restrict__ Sp){
  __shared__ __align__(16) float sT[64*64];
  __shared__ __align__(16) float sW[64][68];
  __shared__ float sc[64];
  int tid = threadIdx.x;
  int bh = blockIdx.x, es = blockIdx.y;
  #pragma unroll
  for (int r=0;r<2;r++){
    int idx = tid + r*256;
    int row = idx>>3, g8 = (idx&7)*8;
    ushort_t tv[8];
    *(uint4*)tv = *(const uint4*)(T + (size_t)(bh*64+row)*3072 + es*64 + g8);
    #pragma unroll
    for (int c=0;c<8;c++) sT[row*64 + g8 + c] = bf2f(tv[c]);
  }
  if (tid < 64) sc[tid] = __expf(lac[(size_t)(bh*64+tid)*64 + 63]);
  __syncthreads();
  if (tid < 64){
    int k = tid;
    float w = 1.f;
    for (int j=63; j>=0; --j){
      bool a = (j < k);
      sW[j][k] = a ? w : 0.f;
      if (a) w *= sc[j];
    }
  }
  __syncthreads();
  int k0 = (tid>>4)*4, e0 = (tid&15)*4;
  float acc[4][4];
  #pragma unroll
  for (int i=0;i<4;i++)
    #pragma unroll
    for (int j=0;j<4;j++) acc[i][j]=0.f;
  int jmax = k0+2; if (jmax > 62) jmax = 62;
  for (int j=0; j<=jmax; ++j){
    float wv[4], tv[4];
    *(float4*)wv = *(float4*)&sW[j][k0];
    *(float4*)tv = *(float4*)&sT[j*64 + e0];
    #pragma unroll
    for (int i=0;i<4;i++)
      #pragma unroll
      for (int e=0;e<4;e++) acc[i][e] = fmaf(wv[i], tv[e], acc[i][e]);
  }
  #pragma unroll
  for (int i=0;i<4;i++){
    ushort4 h4;
    ushort_t* hp = (ushort_t*)&h4;
    #pragma unroll
    for (int e=0;e<4;e++) hp[e] = f2bf(acc[i][e]);
    *(ushort4*)(Sp + (size_t)(bh*64+k0+i)*3072 + es*64 + e0) = h4;
  }
}

// ----- phase3 (MFMA) + fused gate: GM 3-term; intra/carry single-term -----
__global__ __launch_bounds__(256, 3) void k_phase3(
    const float* __restrict__ dtbuf, const float* __restrict__ lac,
    const ushort_t* __restrict__ Bm_h, const ushort_t* __restrict__ Bm_l,
    const ushort_t* __restrict__ Cm_h, const ushort_t* __restrict__ Cm_l,
    const ushort_t* __restrict__ xs,
    const ushort_t* __restrict__ Sp, const float* __restrict__ Dparam,
    const float* __restrict__ xg, const float* __restrict__ Weff,
    const float* __restrict__ beff,
    ushort_t* __restrict__ g16, float* __restrict__ ssum){
  __shared__ __align__(16) ushort_t sCh[64*72], sCl[64*72];   // C[i][n]
  __shared__ __align__(16) ushort_t sBh[64*72], sBl[64*72];   // B[s][n] -> GM[i][s]
  __shared__ __align__(16) ushort_t sXs[48*72];               // X^T[p][s] single
  __shared__ float sla[64], sdt[64];
  int tid = threadIdx.x, blk = blockIdx.x;
  int bh = blk>>6, k = blk&63, b = bh>>3, hh = bh&7, t0 = k*64;
  int w = tid>>6, lane = tid&63, l15 = lane&15, quad = lane>>4;

  if (tid < 64){
    sdt[tid] = dtbuf[(size_t)bh*4096 + t0 + tid];
    sla[tid] = lac[(size_t)blk*64 + tid];
  }
  // ---- stage C, B: pure 16B copies ----
  {
    int row = tid>>2, ng = (tid&3)*16;
    size_t gb = (size_t)(b*4096+t0+row)*64 + ng;
    int o = row*72 + ng;
    *(uint4*)&sCh[o]   = *(const uint4*)(Cm_h + gb);
    *(uint4*)&sCh[o+8] = *(const uint4*)(Cm_h + gb + 8);
    *(uint4*)&sCl[o]   = *(const uint4*)(Cm_l + gb);
    *(uint4*)&sCl[o+8] = *(const uint4*)(Cm_l + gb + 8);
    *(uint4*)&sBh[o]   = *(const uint4*)(Bm_h + gb);
    *(uint4*)&sBh[o+8] = *(const uint4*)(Bm_h + gb + 8);
    *(uint4*)&sBl[o]   = *(const uint4*)(Bm_l + gb);
    *(uint4*)&sBl[o+8] = *(const uint4*)(Bm_l + gb + 8);
  }
  // ---- stage X^T single: copy + pack ----
  {
    int s2 = (tid>>3)*2, p0 = (tid&7)*6;
    const ushort_t* xh0 = xs + (size_t)(bh*4096+t0+s2)*48 + p0;
    #pragma unroll
    for (int c=0;c<6;c++){
      unsigned int hv = (unsigned int)xh0[c] | ((unsigned int)xh0[48+c]<<16);
      *(unsigned int*)&sXs[(p0+c)*72 + s2] = hv;
    }
  }
  __syncthreads();

  // ---- GM mfma: wave w owns i-band w, s-tiles 0..w (3-term split) ----
  f32x4 gacc[4];
  #pragma unroll
  for (int t=0;t<4;t++) gacc[t] = (f32x4)(0.f);
  {
    bf16x8 cah[2], cal[2];
    #pragma unroll
    for (int ks=0;ks<2;ks++){
      int ao = (w*16+l15)*72 + ks*32 + quad*8;
      cah[ks] = *(bf16x8*)&sCh[ao];
      cal[ks] = *(bf16x8*)&sCl[ao];
    }
    for (int bs=0; bs<=w; ++bs){
      #pragma unroll
      for (int ks=0;ks<2;ks++){
        int bo = (bs*16+l15)*72 + ks*32 + quad*8;
        bf16x8 bhf = *(bf16x8*)&sBh[bo];
        bf16x8 blf = *(bf16x8*)&sBl[bo];
        gacc[bs] = __builtin_amdgcn_mfma_f32_16x16x32_bf16(cah[ks], bhf, gacc[bs], 0,0,0);
        gacc[bs] = __builtin_amdgcn_mfma_f32_16x16x32_bf16(cah[ks], blf, gacc[bs], 0,0,0);
        gacc[bs] = __builtin_amdgcn_mfma_f32_16x16x32_bf16(cal[ks], bhf, gacc[bs], 0,0,0);
      }
    }
  }
  __syncthreads();   // sB reads done -> safe to overwrite with GM

  // ---- scale/mask, write GM single bf16 into sBh; zero needed tiles ----
  for (int bs=0; bs<=w; ++bs){
    #pragma unroll
    for (int r=0;r<4;r++){
      int i = w*16 + quad*4 + r;
      int s = bs*16 + l15;
      float v = 0.f;
      if (s <= i) v = gacc[bs][r] * __expf(sla[i]-sla[s]) * sdt[s];
      sBh[i*72+s] = f2bf(v);
    }
  }
  if (w==0){
    #pragma unroll
    for (int r=0;r<4;r++) sBh[(quad*4+r)*72 + 16+l15] = 0;
  }
  if (w==2){
    #pragma unroll
    for (int r=0;r<4;r++) sBh[(32+quad*4+r)*72 + 48+l15] = 0;
  }
  __syncthreads();

  // ---- Sp fragments direct (single bf16, [p][n] layout) ----
  bf16x8 pah[3][2];
  {
    const ushort_t* sph = Sp + (size_t)blk*3072;
    #pragma unroll
    for (int pt=0;pt<3;pt++)
      #pragma unroll
      for (int ks=0;ks<2;ks++)
        pah[pt][ks] = *(const bf16x8*)(sph + (size_t)(pt*16+l15)*64 + ks*32 + quad*8);
  }

  // ---- O = X^T·GM^T (intra; both single -> 1 MFMA/tile) ----
  f32x4 accI[3], accA[3];
  #pragma unroll
  for (int t=0;t<3;t++){ accI[t] = (f32x4)(0.f); accA[t] = (f32x4)(0.f); }
  int nks = (w>=2) ? 2 : 1;
  for (int ks=0; ks<nks; ++ks){
    int go = (w*16+l15)*72 + ks*32 + quad*8;
    bf16x8 gbh = *(bf16x8*)&sBh[go];
    #pragma unroll
    for (int pt=0;pt<3;pt++){
      bf16x8 xas = *(bf16x8*)&sXs[(pt*16+l15)*72 + ks*32 + quad*8];
      accI[pt] = __builtin_amdgcn_mfma_f32_16x16x32_bf16(xas, gbh, accI[pt], 0,0,0);
    }
  }
  // ---- + Sp^T·C^T (carry; Sp single x C_hi -> 1 MFMA/tile) ----
  #pragma unroll
  for (int ks=0; ks<2; ++ks){
    int co = (w*16+l15)*72 + ks*32 + quad*8;
    bf16x8 cbh = *(bf16x8*)&sCh[co];
    #pragma unroll
    for (int pt=0;pt<3;pt++)
      accA[pt] = __builtin_amdgcn_mfma_f32_16x16x32_bf16(pah[pt][ks], cbh, accA[pt], 0,0,0);
  }
  // ---- epilogue: y = accI + e^la*accA + D*x; g = y*silu(z); ssum += g^2 ----
  {
    int i = w*16 + l15;
    int tok = b*4096 + t0 + i;
    float eli = __expf(sla[i]);
    float Dh = Dparam[hh];
    float4 xv = *(const float4*)(xg + (size_t)tok*4);
    ushort_t* gbase = g16 + (size_t)tok*384 + hh*48;
    float ssq = 0.f;
    #pragma unroll
    for (int pt=0;pt<3;pt++)
      #pragma unroll
      for (int r=0;r<4;r++){
        int p = pt*16 + quad*4 + r;
        float xf = bf2f(sXs[p*72 + i]);
        float yv = accI[pt][r] + eli*accA[pt][r] + Dh*xf;
        int e = hh*48 + p;
        float zv = beff[e];
        zv = fmaf(xv.x, Weff[e], zv);
        zv = fmaf(xv.y, Weff[904+e], zv);
        zv = fmaf(xv.z, Weff[1808+e], zv);
        zv = fmaf(xv.w, Weff[2712+e], zv);
        float gg = yv * (zv * sigmoidf_(zv));
        gbase[p] = f2bf(gg);
        ssq += gg*gg;
      }
    ssq += __shfl_xor(ssq, 16);
    ssq += __shfl_xor(ssq, 32);
    if (quad == 0) atomicAdd(&ssum[tok], ssq);
  }
}

// ----- mlp2 (+ fused final via last-block ticket) -----
__global__ __launch_bounds__(256) void k_mlp2(
    const ushort_t* __restrict__ g16, const float* __restrict__ ssum,
    const float* __restrict__ Weff2, const float* __restrict__ b1,
    const float* __restrict__ W2, const float* __restrict__ b2,
    float* __restrict__ macc, unsigned int* __restrict__ cnt,
    const float* __restrict__ Wo, const float* __restrict__ bo,
    float* __restrict__ out){
  __shared__ __align__(16) float sW[384][32];
  __shared__ __align__(16) float sm1[64][33];
  __shared__ __align__(16) float sW2[32][32];
  __shared__ __align__(16) float sm2[64][33];
  __shared__ int slast;
  int tid = threadIdx.x;
  int tok0 = blockIdx.x*64;
  int b = tok0 >> 12;
  #pragma unroll
  for (int r=0;r<12;r++){
    int idx = tid + r*256;
    int row = idx>>3, c4 = (idx&7)*4;
    *(float4*)&sW[row][c4] = *(const float4*)(Weff2 + (size_t)idx*4);
  }
  {
    int row = tid>>3, c4 = (tid&7)*4;
    *(float4*)&sW2[row][c4] = *(const float4*)(W2 + row*32 + c4);
  }
  __syncthreads();
  {
    int tk = tid>>3, j0 = (tid&7)*4;
    float rms0 = rsqrtf(ssum[tok0+tk]*(1.f/384.f) + 1e-5f);
    float rms1 = rsqrtf(ssum[tok0+tk+32]*(1.f/384.f) + 1e-5f);
    float a0[4], a1[4];
    #pragma unroll
    for (int j=0;j<4;j++){ a0[j] = b1[j0+j]; a1[j] = a0[j]; }
    const ushort_t* y0 = g16 + (size_t)(tok0+tk)*384;
    const ushort_t* y1 = g16 + (size_t)(tok0+tk+32)*384;
    for (int k8=0;k8<48;k8++){
      ushort_t ua[8], ub[8];
      *(uint4*)ua = *(const uint4*)(y0 + k8*8);
      *(uint4*)ub = *(const uint4*)(y1 + k8*8);
      #pragma unroll
      for (int c=0;c<8;c++){
        float va = bf2f(ua[c])*rms0, vb = bf2f(ub[c])*rms1;
        float w[4]; *(float4*)w = *(float4*)&sW[k8*8+c][j0];
        #pragma unroll
        for (int j=0;j<4;j++){ a0[j] = fmaf(va, w[j], a0[j]); a1[j] = fmaf(vb, w[j], a1[j]); }
      }
    }
    #pragma unroll
    for (int j=0;j<4;j++){
      sm1[tk][j0+j]    = fmaxf(a0[j], 0.f);
      sm1[tk+32][j0+j] = fmaxf(a1[j], 0.f);
    }
  }
  __syncthreads();
  {
    int tk = tid>>3, j0 = (tid&7)*4;
    float a0[4], a1[4];
    #pragma unroll
    for (int j=0;j<4;j++){ a0[j] = b2[j0+j]; a1[j] = a0[j]; }
    #pragma unroll
    for (int kk=0;kk<32;kk++){
      float va = sm1[tk][kk];
      float vb = sm1[tk+32][kk];
      float w[4]; *(float4*)w = *(float4*)&sW2[kk][j0];
      #pragma unroll
      for (int j=0;j<4;j++){ a0[j] = fmaf(va, w[j], a0[j]); a1[j] = fmaf(vb, w[j], a1[j]); }
    }
    #pragma unroll
    for (int j=0;j<4;j++){
      sm2[tk][j0+j]    = fmaxf(a0[j], 0.f);
      sm2[tk+32][j0+j] = fmaxf(a1[j], 0.f);
    }
  }
  __syncthreads();
  if (tid < 32){
    float t = 0.f;
    #pragma unroll
    for (int tok=0;tok<64;tok++) t += sm2[tok][tid];
    atomicAdd(&macc[b*32 + tid], t);
  }
  __threadfence();
  __syncthreads();
  if (tid == 0){
    unsigned int old = atomicAdd(cnt, 1u);
    slast = (old == (unsigned int)(gridDim.x - 1)) ? 1 : 0;
  }
  __syncthreads();
  if (slast){
    __threadfence();
    if (tid < 4){
      float acc = bo[0];
      #pragma unroll
      for (int j=0;j<32;j++) acc = fmaf(macc[tid*32+j]*(1.f/4096.f), Wo[j], acc);
      out[tid] = acc;
    }
  }
}

// ---------------------------------------------------------------------------
extern "C" void kernel_launch(void* const* d_in, const int* in_sizes, int n_in,
                              void* d_out, int out_size, void* d_ws, size_t ws_size,
                              hipStream_t stream){
  const float* x      = (const float*)d_in[0];
  const float* Wfc    = (const float*)d_in[1];
  const float* bfc    = (const float*)d_in[2];
  const float* W_in   = (const float*)d_in[3];
  const float* conv_w = (const float*)d_in[4];
  const float* conv_b = (const float*)d_in[5];
  const float* dt_bias= (const float*)d_in[6];
  const float* A_log  = (const float*)d_in[7];
  const float* Dparam = (const float*)d_in[8];
  const float* norm_w = (const float*)d_in[9];
  const float* W_out  = (const float*)d_in[10];
  const float* W1     = (const float*)d_in[11];
  const float* b1     = (const float*)d_in[12];
  const float* W2     = (const float*)d_in[13];
  const float* b2     = (const float*)d_in[14];
  const float* Wo     = (const float*)d_in[15];
  const float* bo     = (const float*)d_in[16];
  float* ws  = (float*)d_ws;
  float* out = (float*)d_out;

  float* Weff  = ws + OFF_W;
  float* beff  = ws + OFF_W + 4096;
  float* Weff2 = ws + OFF_W + 8192;
  float* ssum  = ws + OFF_Z;            // 16384 fp32
  ushort_t* Tb   = (ushort_t*)(ws + OFF_T);
  ushort_t* xsb  = (ushort_t*)(ws + OFF_XS);
  ushort_t* Bm_h = (ushort_t*)(ws + OFF_BM);
  ushort_t* Bm_l = Bm_h + 1048576u;     // 16384*64
  ushort_t* Cm_h = (ushort_t*)(ws + OFF_CM);
  ushort_t* Cm_l = Cm_h + 1048576u;
  float* dtb   = ws + OFF_DT;
  float* lacb  = ws + OFF_LAC;
  ushort_t* Spb  = (ushort_t*)(ws + OFF_SP);
  ushort_t* g16 = (ushort_t*)(ws + OFF_Y);
  float* macc  = ws + OFF_MACC;
  unsigned int* cnt = (unsigned int*)(ws + OFF_MACC + 128);

  k_prep<<<dim3(116), dim3(256), 0, stream>>>(Wfc, bfc, W_in, W_out, W1, norm_w,
                                              Weff, beff, Weff2, macc, ssum, cnt);
  k_ipc<<<dim3(BL/4), dim3(256), 0, stream>>>(x, Weff, beff, conv_w, conv_b,
                                              dt_bias, xsb, Bm_h, Bm_l,
                                              Cm_h, Cm_l, dtb);
  k_phase1<<<dim3(BH*NC), dim3(256), 0, stream>>>(dtb, Bm_h, xsb, A_log, Tb, lacb);
  k_phase2p<<<dim3(BH,48), dim3(256), 0, stream>>>(Tb, lacb, Spb);
  k_phase3<<<dim3(BH*NC), dim3(256), 0, stream>>>(dtb, lacb, Bm_h, Bm_l,
                                                  Cm_h, Cm_l, xsb,
                                                  Spb, Dparam, x, Weff, beff,
                                                  g16, ssum);
  k_mlp2<<<dim3(BL/64), dim3(256), 0, stream>>>(g16, ssum, Weff2, b1, W2, b2,
                                                macc, cnt, Wo, bo, out);
}

// Round 19
// 181.437 us; speedup vs baseline: 1.0659x; 1.0659x over previous
//
#include <hip/hip_runtime.h>
#include <math.h>

// ---------------------------------------------------------------------------
// MambaAnglePredictor — Round 19 (R18 with last-block ticket reverted):
//   xs single bf16; phase1 all-single (6 MFMAs); phase3 intra/carry single;
//   separate k_final restored (ticket's 256 device fences cost > 1 launch).
// ---------------------------------------------------------------------------

#define BDIM 4
#define LDIM 4096
#define BL (BDIM*LDIM)      // 16384 tokens
#define QC 64
#define NC (LDIM/QC)        // 64
#define BH (BDIM*NH)        // 32
#define NH 8

// workspace offsets (floats)
#define OFF_W    0u          // Weff 4x904 @0, beff @4096, Weff2 @8192
#define OFF_Z    3145728u    // ssum fp32 [16384]
#define OFF_T    9437184u    // T bf16 [p][n] per chunk
#define OFF_XS   17825792u   // xs single bf16
#define OFF_BM   24117248u   // Bm_h | Bm_l
#define OFF_CM   25165824u   // Cm_h | Cm_l
#define OFF_DT   26214400u   // 32*4096 fp32
#define OFF_LAC  26345472u   // 2048*64 fp32
#define OFF_SP   26476544u   // Sp bf16 [p][n] per chunk
#define OFF_Y    32768000u   // g bf16 (gated y, pre-RMS)
#define OFF_MACC 39059456u   // 4*32 fp32

typedef unsigned short ushort_t;
typedef __attribute__((ext_vector_type(8))) short bf16x8;
typedef __attribute__((ext_vector_type(4))) float f32x4;

__device__ __forceinline__ float sigmoidf_(float x){ return 1.0f/(1.0f+__expf(-x)); }
__device__ __forceinline__ ushort_t f2bf(float x){
  unsigned int u = __float_as_uint(x);
  u += 0x7fffu + ((u>>16)&1u);
  return (ushort_t)(u>>16);
}
__device__ __forceinline__ float bf2f(ushort_t h){
  return __uint_as_float(((unsigned int)h)<<16);
}

// ----- prep: Weff, beff, Weff2 (nw-folded), macc/ssum zero -----
__global__ void k_prep(const float* __restrict__ Wfc, const float* __restrict__ bfc,
                       const float* __restrict__ W_in, const float* __restrict__ W_out,
                       const float* __restrict__ W1, const float* __restrict__ norm_w,
                       float* __restrict__ Weff, float* __restrict__ beff,
                       float* __restrict__ Weff2, float* __restrict__ macc,
                       float* __restrict__ ssum){
  int blk = blockIdx.x, tid = threadIdx.x;
  if (blk < 4){
    int n = blk*256 + tid;
    if (n >= 904) return;
    float a0=0.f,a1=0.f,a2=0.f,a3=0.f,ab=0.f;
    for (int d=0; d<192; d++){
      float w = W_in[(size_t)d*904 + n];
      a0 = fmaf(Wfc[d], w, a0);
      a1 = fmaf(Wfc[192+d], w, a1);
      a2 = fmaf(Wfc[384+d], w, a2);
      a3 = fmaf(Wfc[576+d], w, a3);
      ab = fmaf(bfc[d], w, ab);
    }
    Weff[n] = a0; Weff[904+n] = a1; Weff[1808+n] = a2; Weff[2712+n] = a3;
    beff[n] = ab;
  } else if (blk < 52){
    if (blk == 4 && tid < 128) macc[tid] = 0.f;
    int g = (blk-4)*256 + tid;
    int i = g>>5, j = g&31;
    float a = 0.f;
    for (int d=0; d<192; d++) a = fmaf(W_out[(size_t)i*192+d], W1[d*32+j], a);
    Weff2[g] = a * norm_w[i];
  } else {
    int idx = (blk-52)*256 + tid;       // 64 blocks * 256 = 16384
    ssum[idx] = 0.f;
  }
}

// ----- ipc: fused in_proj+conv+silu+dt; 4 tokens/block; xs single bf16 -----
__global__ __launch_bounds__(256) void k_ipc(
    const float* __restrict__ x, const float* __restrict__ Weff,
    const float* __restrict__ beff, const float* __restrict__ conv_w,
    const float* __restrict__ conv_b, const float* __restrict__ dt_bias,
    ushort_t* __restrict__ xs,
    ushort_t* __restrict__ Bm_h, ushort_t* __restrict__ Bm_l,
    ushort_t* __restrict__ Cm_h, ushort_t* __restrict__ Cm_l,
    float* __restrict__ dtb){
  __shared__ float sx[7][4];            // x rows l0-3 .. l0+3
  int pb = blockIdx.x, tid = threadIdx.x;
  int bl0 = pb*4;
  int l0 = bl0 & 4095, b = bl0 >> 12;
  if (tid < 28){
    int row = tid>>2, r = tid&3;
    int ll = l0-3+row;
    sx[row][r] = (ll>=0) ? x[(size_t)(b*4096+ll)*4 + r] : 0.f;
  }
  __syncthreads();
  if (tid < 32){
    int t = tid>>3, hh = tid&7;
    float raw = beff[896+hh];
    #pragma unroll
    for (int r=0;r<4;r++) raw = fmaf(sx[3+t][r], Weff[r*904+896+hh], raw);
    float xx = raw + dt_bias[hh];
    float dtv = (xx > 20.f) ? xx : log1pf(__expf(xx));
    dtb[(size_t)(b*8+hh)*4096 + l0 + t] = dtv;
  }
  #pragma unroll
  for (int half=0; half<2; half++){
    int c = tid + half*256;
    float w0 = Weff[384+c];
    float w1 = Weff[904+384+c];
    float w2 = Weff[1808+384+c];
    float w3 = Weff[2712+384+c];
    float bb = beff[384+c];
    float cw0 = conv_w[c], cw1 = conv_w[512+c], cw2 = conv_w[1024+c], cw3 = conv_w[1536+c];
    float cb = conv_b[c];
    float pre[7];
    #pragma unroll
    for (int q=0;q<7;q++){
      int ll = l0-3+q;
      float xv = bb;
      xv = fmaf(sx[q][0], w0, xv);
      xv = fmaf(sx[q][1], w1, xv);
      xv = fmaf(sx[q][2], w2, xv);
      xv = fmaf(sx[q][3], w3, xv);
      pre[q] = (ll >= 0) ? xv : 0.f;
    }
    float av[4];
    #pragma unroll
    for (int t=0;t<4;t++){
      float a = cb;
      a = fmaf(cw0,pre[t+0],a); a = fmaf(cw1,pre[t+1],a);
      a = fmaf(cw2,pre[t+2],a); a = fmaf(cw3,pre[t+3],a);
      av[t] = a * sigmoidf_(a);
    }
    if (c < 384){
      int hh = c / 48, p = c - hh*48;
      size_t idx = (size_t)((b*8+hh)*4096 + l0)*48 + p;
      #pragma unroll
      for (int t=0;t<4;t++) xs[idx + t*48] = f2bf(av[t]);
    } else if (c < 448){
      size_t idx = (size_t)bl0*64 + (c-384);
      #pragma unroll
      for (int t=0;t<4;t++){
        ushort_t h = f2bf(av[t]);
        Bm_h[idx + t*64] = h;
        Bm_l[idx + t*64] = f2bf(av[t] - bf2f(h));
      }
    } else {
      size_t idx = (size_t)bl0*64 + (c-448);
      #pragma unroll
      for (int t=0;t<4;t++){
        ushort_t h = f2bf(av[t]);
        Cm_h[idx + t*64] = h;
        Cm_l[idx + t*64] = f2bf(av[t] - bf2f(h));
      }
    }
  }
}

// ----- phase1 (MFMA, all-single): T^T[p][n] = X^T · Bw; 6 MFMAs -----
__global__ __launch_bounds__(256, 3) void k_phase1(
    const float* __restrict__ dtbuf,
    const ushort_t* __restrict__ Bm_h,
    const ushort_t* __restrict__ xs,
    const float* __restrict__ A_log,
    ushort_t* __restrict__ T, float* __restrict__ lac){
  __shared__ __align__(16) ushort_t sBs[64*72];   // Bw^T [n][s] single
  __shared__ __align__(16) ushort_t sXs[48*72];   // X^T [p][s] single
  __shared__ float sdt[64], sla[64], sw[64];
  int tid = threadIdx.x, blk = blockIdx.x;
  int bh = blk >> 6, k = blk & 63;
  int b = bh >> 3, hh = bh & 7;
  int t0 = k*64;
  int w = tid>>6, lane = tid&63, l15 = lane&15, quad = lane>>4;

  if (tid < 64) sdt[tid] = dtbuf[(size_t)bh*4096 + t0 + tid];
  __syncthreads();
  if (tid == 0){
    float eA = __expf(A_log[hh]);
    float cum = 0.f;
    for (int i=0;i<64;i++){ cum -= sdt[i]*eA; sla[i] = cum; }
  }
  __syncthreads();
  if (tid < 64){
    sw[tid] = __expf(sla[63]-sla[tid])*sdt[tid];
    lac[(size_t)blk*64 + tid] = sla[tid];
  }
  __syncthreads();
  // ---- stage Bw^T [n][s]: B single, scale by sw, round once ----
  {
    int s2 = (tid&31)*2, ng = (tid>>5)*8;
    size_t base0 = (size_t)(b*4096+t0+s2)*64 + ng;
    ushort_t h0a[8], h1a[8];
    *(uint4*)h0a = *(const uint4*)(Bm_h + base0);
    *(uint4*)h1a = *(const uint4*)(Bm_h + base0 + 64);
    float w0 = sw[s2], w1 = sw[s2+1];
    #pragma unroll
    for (int c=0;c<8;c++){
      ushort_t h0 = f2bf(bf2f(h0a[c]) * w0);
      ushort_t h1 = f2bf(bf2f(h1a[c]) * w1);
      *(unsigned int*)&sBs[(ng+c)*72 + s2] = (unsigned int)h0 | ((unsigned int)h1<<16);
    }
  }
  // ---- stage X^T [p][s]: pure copy + pack ----
  {
    int s2 = (tid>>3)*2, p0 = (tid&7)*6;
    const ushort_t* xh0 = xs + (size_t)(bh*4096+t0+s2)*48 + p0;
    #pragma unroll
    for (int c=0;c<6;c++){
      unsigned int hv = (unsigned int)xh0[c] | ((unsigned int)xh0[48+c]<<16);
      *(unsigned int*)&sXs[(p0+c)*72 + s2] = hv;
    }
  }
  __syncthreads();
  f32x4 acc[3];
  #pragma unroll
  for (int t=0;t<3;t++) acc[t] = (f32x4)(0.f);
  #pragma unroll
  for (int ks=0;ks<2;ks++){
    int bo = (w*16+l15)*72 + ks*32 + quad*8;
    bf16x8 bbs = *(bf16x8*)&sBs[bo];
    #pragma unroll
    for (int pt=0;pt<3;pt++){
      int xo = (pt*16+l15)*72 + ks*32 + quad*8;
      bf16x8 xas = *(bf16x8*)&sXs[xo];
      acc[pt] = __builtin_amdgcn_mfma_f32_16x16x32_bf16(xas, bbs, acc[pt], 0,0,0);
    }
  }
  {
    ushort_t* dst = T + (size_t)blk*3072;
    #pragma unroll
    for (int pt=0;pt<3;pt++)
      #pragma unroll
      for (int r=0;r<4;r++)
        dst[(pt*16+quad*4+r)*64 + w*16 + l15] = f2bf(acc[pt][r]);
  }
}

// ----- phase2p: Sp[k] = sum_{j<k} W[k][j] T[j]; T bf16 in, Sp bf16 out -----
__global__ __launch_bounds__(256) void k_phase2p(
    const ushort_t* __restrict__ T, const float* __restrict__ lac,
    ushort_t* __restrict__ Sp){
  __shared__ __align__(16) float sT[64*64];
  __shared__ __align__(16) float sW[64][68];
  __shared__ float sc[64];
  int tid = threadIdx.x;
  int bh = blockIdx.x, es = blockIdx.y;
  #pragma unroll
  for (int r=0;r<2;r++){
    int idx = tid + r*256;
    int row = idx>>3, g8 = (idx&7)*8;
    ushort_t tv[8];
    *(uint4*)tv = *(const uint4*)(T + (size_t)(bh*64+row)*3072 + es*64 + g8);
    #pragma unroll
    for (int c=0;c<8;c++) sT[row*64 + g8 + c] = bf2f(tv[c]);
  }
  if (tid < 64) sc[tid] = __expf(lac[(size_t)(bh*64+tid)*64 + 63]);
  __syncthreads();
  if (tid < 64){
    int k = tid;
    float w = 1.f;
    for (int j=63; j>=0; --j){
      bool a = (j < k);
      sW[j][k] = a ? w : 0.f;
      if (a) w *= sc[j];
    }
  }
  __syncthreads();
  int k0 = (tid>>4)*4, e0 = (tid&15)*4;
  float acc[4][4];
  #pragma unroll
  for (int i=0;i<4;i++)
    #pragma unroll
    for (int j=0;j<4;j++) acc[i][j]=0.f;
  int jmax = k0+2; if (jmax > 62) jmax = 62;
  for (int j=0; j<=jmax; ++j){
    float wv[4], tv[4];
    *(float4*)wv = *(float4*)&sW[j][k0];
    *(float4*)tv = *(float4*)&sT[j*64 + e0];
    #pragma unroll
    for (int i=0;i<4;i++)
      #pragma unroll
      for (int e=0;e<4;e++) acc[i][e] = fmaf(wv[i], tv[e], acc[i][e]);
  }
  #pragma unroll
  for (int i=0;i<4;i++){
    ushort4 h4;
    ushort_t* hp = (ushort_t*)&h4;
    #pragma unroll
    for (int e=0;e<4;e++) hp[e] = f2bf(acc[i][e]);
    *(ushort4*)(Sp + (size_t)(bh*64+k0+i)*3072 + es*64 + e0) = h4;
  }
}

// ----- phase3 (MFMA) + fused gate: GM 3-term; intra/carry single-term -----
__global__ __launch_bounds__(256, 3) void k_phase3(
    const float* __restrict__ dtbuf, const float* __restrict__ lac,
    const ushort_t* __restrict__ Bm_h, const ushort_t* __restrict__ Bm_l,
    const ushort_t* __restrict__ Cm_h, const ushort_t* __restrict__ Cm_l,
    const ushort_t* __restrict__ xs,
    const ushort_t* __restrict__ Sp, const float* __restrict__ Dparam,
    const float* __restrict__ xg, const float* __restrict__ Weff,
    const float* __restrict__ beff,
    ushort_t* __restrict__ g16, float* __restrict__ ssum){
  __shared__ __align__(16) ushort_t sCh[64*72], sCl[64*72];   // C[i][n]
  __shared__ __align__(16) ushort_t sBh[64*72], sBl[64*72];   // B[s][n] -> GM[i][s]
  __shared__ __align__(16) ushort_t sXs[48*72];               // X^T[p][s] single
  __shared__ float sla[64], sdt[64];
  int tid = threadIdx.x, blk = blockIdx.x;
  int bh = blk>>6, k = blk&63, b = bh>>3, hh = bh&7, t0 = k*64;
  int w = tid>>6, lane = tid&63, l15 = lane&15, quad = lane>>4;

  if (tid < 64){
    sdt[tid] = dtbuf[(size_t)bh*4096 + t0 + tid];
    sla[tid] = lac[(size_t)blk*64 + tid];
  }
  // ---- stage C, B: pure 16B copies ----
  {
    int row = tid>>2, ng = (tid&3)*16;
    size_t gb = (size_t)(b*4096+t0+row)*64 + ng;
    int o = row*72 + ng;
    *(uint4*)&sCh[o]   = *(const uint4*)(Cm_h + gb);
    *(uint4*)&sCh[o+8] = *(const uint4*)(Cm_h + gb + 8);
    *(uint4*)&sCl[o]   = *(const uint4*)(Cm_l + gb);
    *(uint4*)&sCl[o+8] = *(const uint4*)(Cm_l + gb + 8);
    *(uint4*)&sBh[o]   = *(const uint4*)(Bm_h + gb);
    *(uint4*)&sBh[o+8] = *(const uint4*)(Bm_h + gb + 8);
    *(uint4*)&sBl[o]   = *(const uint4*)(Bm_l + gb);
    *(uint4*)&sBl[o+8] = *(const uint4*)(Bm_l + gb + 8);
  }
  // ---- stage X^T single: copy + pack ----
  {
    int s2 = (tid>>3)*2, p0 = (tid&7)*6;
    const ushort_t* xh0 = xs + (size_t)(bh*4096+t0+s2)*48 + p0;
    #pragma unroll
    for (int c=0;c<6;c++){
      unsigned int hv = (unsigned int)xh0[c] | ((unsigned int)xh0[48+c]<<16);
      *(unsigned int*)&sXs[(p0+c)*72 + s2] = hv;
    }
  }
  __syncthreads();

  // ---- GM mfma: wave w owns i-band w, s-tiles 0..w (3-term split) ----
  f32x4 gacc[4];
  #pragma unroll
  for (int t=0;t<4;t++) gacc[t] = (f32x4)(0.f);
  {
    bf16x8 cah[2], cal[2];
    #pragma unroll
    for (int ks=0;ks<2;ks++){
      int ao = (w*16+l15)*72 + ks*32 + quad*8;
      cah[ks] = *(bf16x8*)&sCh[ao];
      cal[ks] = *(bf16x8*)&sCl[ao];
    }
    for (int bs=0; bs<=w; ++bs){
      #pragma unroll
      for (int ks=0;ks<2;ks++){
        int bo = (bs*16+l15)*72 + ks*32 + quad*8;
        bf16x8 bhf = *(bf16x8*)&sBh[bo];
        bf16x8 blf = *(bf16x8*)&sBl[bo];
        gacc[bs] = __builtin_amdgcn_mfma_f32_16x16x32_bf16(cah[ks], bhf, gacc[bs], 0,0,0);
        gacc[bs] = __builtin_amdgcn_mfma_f32_16x16x32_bf16(cah[ks], blf, gacc[bs], 0,0,0);
        gacc[bs] = __builtin_amdgcn_mfma_f32_16x16x32_bf16(cal[ks], bhf, gacc[bs], 0,0,0);
      }
    }
  }
  __syncthreads();   // sB reads done -> safe to overwrite with GM

  // ---- scale/mask, write GM single bf16 into sBh; zero needed tiles ----
  for (int bs=0; bs<=w; ++bs){
    #pragma unroll
    for (int r=0;r<4;r++){
      int i = w*16 + quad*4 + r;
      int s = bs*16 + l15;
      float v = 0.f;
      if (s <= i) v = gacc[bs][r] * __expf(sla[i]-sla[s]) * sdt[s];
      sBh[i*72+s] = f2bf(v);
    }
  }
  if (w==0){
    #pragma unroll
    for (int r=0;r<4;r++) sBh[(quad*4+r)*72 + 16+l15] = 0;
  }
  if (w==2){
    #pragma unroll
    for (int r=0;r<4;r++) sBh[(32+quad*4+r)*72 + 48+l15] = 0;
  }
  __syncthreads();

  // ---- Sp fragments direct (single bf16, [p][n] layout) ----
  bf16x8 pah[3][2];
  {
    const ushort_t* sph = Sp + (size_t)blk*3072;
    #pragma unroll
    for (int pt=0;pt<3;pt++)
      #pragma unroll
      for (int ks=0;ks<2;ks++)
        pah[pt][ks] = *(const bf16x8*)(sph + (size_t)(pt*16+l15)*64 + ks*32 + quad*8);
  }

  // ---- O = X^T·GM^T (intra; both single -> 1 MFMA/tile) ----
  f32x4 accI[3], accA[3];
  #pragma unroll
  for (int t=0;t<3;t++){ accI[t] = (f32x4)(0.f); accA[t] = (f32x4)(0.f); }
  int nks = (w>=2) ? 2 : 1;
  for (int ks=0; ks<nks; ++ks){
    int go = (w*16+l15)*72 + ks*32 + quad*8;
    bf16x8 gbh = *(bf16x8*)&sBh[go];
    #pragma unroll
    for (int pt=0;pt<3;pt++){
      bf16x8 xas = *(bf16x8*)&sXs[(pt*16+l15)*72 + ks*32 + quad*8];
      accI[pt] = __builtin_amdgcn_mfma_f32_16x16x32_bf16(xas, gbh, accI[pt], 0,0,0);
    }
  }
  // ---- + Sp^T·C^T (carry; Sp single x C_hi -> 1 MFMA/tile) ----
  #pragma unroll
  for (int ks=0; ks<2; ++ks){
    int co = (w*16+l15)*72 + ks*32 + quad*8;
    bf16x8 cbh = *(bf16x8*)&sCh[co];
    #pragma unroll
    for (int pt=0;pt<3;pt++)
      accA[pt] = __builtin_amdgcn_mfma_f32_16x16x32_bf16(pah[pt][ks], cbh, accA[pt], 0,0,0);
  }
  // ---- epilogue: y = accI + e^la*accA + D*x; g = y*silu(z); ssum += g^2 ----
  {
    int i = w*16 + l15;
    int tok = b*4096 + t0 + i;
    float eli = __expf(sla[i]);
    float Dh = Dparam[hh];
    float4 xv = *(const float4*)(xg + (size_t)tok*4);
    ushort_t* gbase = g16 + (size_t)tok*384 + hh*48;
    float ssq = 0.f;
    #pragma unroll
    for (int pt=0;pt<3;pt++)
      #pragma unroll
      for (int r=0;r<4;r++){
        int p = pt*16 + quad*4 + r;
        float xf = bf2f(sXs[p*72 + i]);
        float yv = accI[pt][r] + eli*accA[pt][r] + Dh*xf;
        int e = hh*48 + p;
        float zv = beff[e];
        zv = fmaf(xv.x, Weff[e], zv);
        zv = fmaf(xv.y, Weff[904+e], zv);
        zv = fmaf(xv.z, Weff[1808+e], zv);
        zv = fmaf(xv.w, Weff[2712+e], zv);
        float gg = yv * (zv * sigmoidf_(zv));
        gbase[p] = f2bf(gg);
        ssq += gg*gg;
      }
    ssq += __shfl_xor(ssq, 16);
    ssq += __shfl_xor(ssq, 32);
    if (quad == 0) atomicAdd(&ssum[tok], ssq);
  }
}

// ----- mlp2: 64 tokens/block, 2 tokens/thread; g bf16 + rms(ssum) inline -----
__global__ __launch_bounds__(256) void k_mlp2(
    const ushort_t* __restrict__ g16, const float* __restrict__ ssum,
    const float* __restrict__ Weff2, const float* __restrict__ b1,
    const float* __restrict__ W2, const float* __restrict__ b2,
    float* __restrict__ macc){
  __shared__ __align__(16) float sW[384][32];
  __shared__ __align__(16) float sm1[64][33];
  __shared__ __align__(16) float sW2[32][32];
  __shared__ __align__(16) float sm2[64][33];
  int tid = threadIdx.x;
  int tok0 = blockIdx.x*64;
  int b = tok0 >> 12;
  #pragma unroll
  for (int r=0;r<12;r++){
    int idx = tid + r*256;
    int row = idx>>3, c4 = (idx&7)*4;
    *(float4*)&sW[row][c4] = *(const float4*)(Weff2 + (size_t)idx*4);
  }
  {
    int row = tid>>3, c4 = (tid&7)*4;
    *(float4*)&sW2[row][c4] = *(const float4*)(W2 + row*32 + c4);
  }
  __syncthreads();
  {
    int tk = tid>>3, j0 = (tid&7)*4;
    float rms0 = rsqrtf(ssum[tok0+tk]*(1.f/384.f) + 1e-5f);
    float rms1 = rsqrtf(ssum[tok0+tk+32]*(1.f/384.f) + 1e-5f);
    float a0[4], a1[4];
    #pragma unroll
    for (int j=0;j<4;j++){ a0[j] = b1[j0+j]; a1[j] = a0[j]; }
    const ushort_t* y0 = g16 + (size_t)(tok0+tk)*384;
    const ushort_t* y1 = g16 + (size_t)(tok0+tk+32)*384;
    for (int k8=0;k8<48;k8++){
      ushort_t ua[8], ub[8];
      *(uint4*)ua = *(const uint4*)(y0 + k8*8);
      *(uint4*)ub = *(const uint4*)(y1 + k8*8);
      #pragma unroll
      for (int c=0;c<8;c++){
        float va = bf2f(ua[c])*rms0, vb = bf2f(ub[c])*rms1;
        float w[4]; *(float4*)w = *(float4*)&sW[k8*8+c][j0];
        #pragma unroll
        for (int j=0;j<4;j++){ a0[j] = fmaf(va, w[j], a0[j]); a1[j] = fmaf(vb, w[j], a1[j]); }
      }
    }
    #pragma unroll
    for (int j=0;j<4;j++){
      sm1[tk][j0+j]    = fmaxf(a0[j], 0.f);
      sm1[tk+32][j0+j] = fmaxf(a1[j], 0.f);
    }
  }
  __syncthreads();
  {
    int tk = tid>>3, j0 = (tid&7)*4;
    float a0[4], a1[4];
    #pragma unroll
    for (int j=0;j<4;j++){ a0[j] = b2[j0+j]; a1[j] = a0[j]; }
    #pragma unroll
    for (int kk=0;kk<32;kk++){
      float va = sm1[tk][kk];
      float vb = sm1[tk+32][kk];
      float w[4]; *(float4*)w = *(float4*)&sW2[kk][j0];
      #pragma unroll
      for (int j=0;j<4;j++){ a0[j] = fmaf(va, w[j], a0[j]); a1[j] = fmaf(vb, w[j], a1[j]); }
    }
    #pragma unroll
    for (int j=0;j<4;j++){
      sm2[tk][j0+j]    = fmaxf(a0[j], 0.f);
      sm2[tk+32][j0+j] = fmaxf(a1[j], 0.f);
    }
  }
  __syncthreads();
  if (tid < 32){
    float t = 0.f;
    #pragma unroll
    for (int tok=0;tok<64;tok++) t += sm2[tok][tid];
    atomicAdd(&macc[b*32 + tid], t);
  }
}

// ----- final: angle[b] = mean_m @ Wo + bo -----
__global__ void k_final(const float* __restrict__ macc, const float* __restrict__ Wo,
                        const float* __restrict__ bo, float* __restrict__ out){
  int tid = threadIdx.x;
  if (tid < 4){
    float acc = bo[0];
    #pragma unroll
    for (int j=0;j<32;j++) acc = fmaf(macc[tid*32+j]*(1.f/4096.f), Wo[j], acc);
    out[tid] = acc;
  }
}

// ---------------------------------------------------------------------------
extern "C" void kernel_launch(void* const* d_in, const int* in_sizes, int n_in,
                              void* d_out, int out_size, void* d_ws, size_t ws_size,
                              hipStream_t stream){
  const float* x      = (const float*)d_in[0];
  const float* Wfc    = (const float*)d_in[1];
  const float* bfc    = (const float*)d_in[2];
  const float* W_in   = (const float*)d_in[3];
  const float* conv_w = (const float*)d_in[4];
  const float* conv_b = (const float*)d_in[5];
  const float* dt_bias= (const float*)d_in[6];
  const float* A_log  = (const float*)d_in[7];
  const float* Dparam = (const float*)d_in[8];
  const float* norm_w = (const float*)d_in[9];
  const float* W_out  = (const float*)d_in[10];
  const float* W1     = (const float*)d_in[11];
  const float* b1     = (const float*)d_in[12];
  const float* W2     = (const float*)d_in[13];
  const float* b2     = (const float*)d_in[14];
  const float* Wo     = (const float*)d_in[15];
  const float* bo     = (const float*)d_in[16];
  float* ws  = (float*)d_ws;
  float* out = (float*)d_out;

  float* Weff  = ws + OFF_W;
  float* beff  = ws + OFF_W + 4096;
  float* Weff2 = ws + OFF_W + 8192;
  float* ssum  = ws + OFF_Z;            // 16384 fp32
  ushort_t* Tb   = (ushort_t*)(ws + OFF_T);
  ushort_t* xsb  = (ushort_t*)(ws + OFF_XS);
  ushort_t* Bm_h = (ushort_t*)(ws + OFF_BM);
  ushort_t* Bm_l = Bm_h + 1048576u;     // 16384*64
  ushort_t* Cm_h = (ushort_t*)(ws + OFF_CM);
  ushort_t* Cm_l = Cm_h + 1048576u;
  float* dtb   = ws + OFF_DT;
  float* lacb  = ws + OFF_LAC;
  ushort_t* Spb  = (ushort_t*)(ws + OFF_SP);
  ushort_t* g16 = (ushort_t*)(ws + OFF_Y);
  float* macc  = ws + OFF_MACC;

  k_prep<<<dim3(116), dim3(256), 0, stream>>>(Wfc, bfc, W_in, W_out, W1, norm_w,
                                              Weff, beff, Weff2, macc, ssum);
  k_ipc<<<dim3(BL/4), dim3(256), 0, stream>>>(x, Weff, beff, conv_w, conv_b,
                                              dt_bias, xsb, Bm_h, Bm_l,
                                              Cm_h, Cm_l, dtb);
  k_phase1<<<dim3(BH*NC), dim3(256), 0, stream>>>(dtb, Bm_h, xsb, A_log, Tb, lacb);
  k_phase2p<<<dim3(BH,48), dim3(256), 0, stream>>>(Tb, lacb, Spb);
  k_phase3<<<dim3(BH*NC), dim3(256), 0, stream>>>(dtb, lacb, Bm_h, Bm_l,
                                                  Cm_h, Cm_l, xsb,
                                                  Spb, Dparam, x, Weff, beff,
                                                  g16, ssum);
  k_mlp2<<<dim3(BL/64), dim3(256), 0, stream>>>(g16, ssum, Weff2, b1, W2, b2, macc);
  k_final<<<dim3(1), dim3(64), 0, stream>>>(macc, Wo, bo, out);
}

// Round 20
// 179.863 us; speedup vs baseline: 1.0752x; 1.0087x over previous
//
#include <hip/hip_runtime.h>
#include <math.h>

// ---------------------------------------------------------------------------
// MambaAnglePredictor — Round 20 (R19 +):
//   mlp2: 32 tokens/block (512 blocks, 2 blk/CU) — fixes 1-block/CU starvation
//   ipc: 8 tokens/block (weights amortized 8x)
// ---------------------------------------------------------------------------

#define BDIM 4
#define LDIM 4096
#define BL (BDIM*LDIM)      // 16384 tokens
#define QC 64
#define NC (LDIM/QC)        // 64
#define BH (BDIM*NH)        // 32
#define NH 8

// workspace offsets (floats)
#define OFF_W    0u          // Weff 4x904 @0, beff @4096, Weff2 @8192
#define OFF_Z    3145728u    // ssum fp32 [16384]
#define OFF_T    9437184u    // T bf16 [p][n] per chunk
#define OFF_XS   17825792u   // xs single bf16
#define OFF_BM   24117248u   // Bm_h | Bm_l
#define OFF_CM   25165824u   // Cm_h | Cm_l
#define OFF_DT   26214400u   // 32*4096 fp32
#define OFF_LAC  26345472u   // 2048*64 fp32
#define OFF_SP   26476544u   // Sp bf16 [p][n] per chunk
#define OFF_Y    32768000u   // g bf16 (gated y, pre-RMS)
#define OFF_MACC 39059456u   // 4*32 fp32

typedef unsigned short ushort_t;
typedef __attribute__((ext_vector_type(8))) short bf16x8;
typedef __attribute__((ext_vector_type(4))) float f32x4;

__device__ __forceinline__ float sigmoidf_(float x){ return 1.0f/(1.0f+__expf(-x)); }
__device__ __forceinline__ ushort_t f2bf(float x){
  unsigned int u = __float_as_uint(x);
  u += 0x7fffu + ((u>>16)&1u);
  return (ushort_t)(u>>16);
}
__device__ __forceinline__ float bf2f(ushort_t h){
  return __uint_as_float(((unsigned int)h)<<16);
}

// ----- prep: Weff, beff, Weff2 (nw-folded), macc/ssum zero -----
__global__ void k_prep(const float* __restrict__ Wfc, const float* __restrict__ bfc,
                       const float* __restrict__ W_in, const float* __restrict__ W_out,
                       const float* __restrict__ W1, const float* __restrict__ norm_w,
                       float* __restrict__ Weff, float* __restrict__ beff,
                       float* __restrict__ Weff2, float* __restrict__ macc,
                       float* __restrict__ ssum){
  int blk = blockIdx.x, tid = threadIdx.x;
  if (blk < 4){
    int n = blk*256 + tid;
    if (n >= 904) return;
    float a0=0.f,a1=0.f,a2=0.f,a3=0.f,ab=0.f;
    for (int d=0; d<192; d++){
      float w = W_in[(size_t)d*904 + n];
      a0 = fmaf(Wfc[d], w, a0);
      a1 = fmaf(Wfc[192+d], w, a1);
      a2 = fmaf(Wfc[384+d], w, a2);
      a3 = fmaf(Wfc[576+d], w, a3);
      ab = fmaf(bfc[d], w, ab);
    }
    Weff[n] = a0; Weff[904+n] = a1; Weff[1808+n] = a2; Weff[2712+n] = a3;
    beff[n] = ab;
  } else if (blk < 52){
    if (blk == 4 && tid < 128) macc[tid] = 0.f;
    int g = (blk-4)*256 + tid;
    int i = g>>5, j = g&31;
    float a = 0.f;
    for (int d=0; d<192; d++) a = fmaf(W_out[(size_t)i*192+d], W1[d*32+j], a);
    Weff2[g] = a * norm_w[i];
  } else {
    int idx = (blk-52)*256 + tid;       // 64 blocks * 256 = 16384
    ssum[idx] = 0.f;
  }
}

// ----- ipc: fused in_proj+conv+silu+dt; 8 tokens/block -----
__global__ __launch_bounds__(256) void k_ipc(
    const float* __restrict__ x, const float* __restrict__ Weff,
    const float* __restrict__ beff, const float* __restrict__ conv_w,
    const float* __restrict__ conv_b, const float* __restrict__ dt_bias,
    ushort_t* __restrict__ xs,
    ushort_t* __restrict__ Bm_h, ushort_t* __restrict__ Bm_l,
    ushort_t* __restrict__ Cm_h, ushort_t* __restrict__ Cm_l,
    float* __restrict__ dtb){
  __shared__ float sx[11][4];           // x rows l0-3 .. l0+7
  int pb = blockIdx.x, tid = threadIdx.x;
  int bl0 = pb*8;
  int l0 = bl0 & 4095, b = bl0 >> 12;
  if (tid < 44){
    int row = tid>>2, r = tid&3;
    int ll = l0-3+row;
    sx[row][r] = (ll>=0) ? x[(size_t)(b*4096+ll)*4 + r] : 0.f;
  }
  __syncthreads();
  if (tid < 64){
    int t = tid>>3, hh = tid&7;
    float raw = beff[896+hh];
    #pragma unroll
    for (int r=0;r<4;r++) raw = fmaf(sx[3+t][r], Weff[r*904+896+hh], raw);
    float xx = raw + dt_bias[hh];
    float dtv = (xx > 20.f) ? xx : log1pf(__expf(xx));
    dtb[(size_t)(b*8+hh)*4096 + l0 + t] = dtv;
  }
  #pragma unroll
  for (int half=0; half<2; half++){
    int c = tid + half*256;
    float w0 = Weff[384+c];
    float w1 = Weff[904+384+c];
    float w2 = Weff[1808+384+c];
    float w3 = Weff[2712+384+c];
    float bb = beff[384+c];
    float cw0 = conv_w[c], cw1 = conv_w[512+c], cw2 = conv_w[1024+c], cw3 = conv_w[1536+c];
    float cb = conv_b[c];
    float pre[11];
    #pragma unroll
    for (int q=0;q<11;q++){
      int ll = l0-3+q;
      float xv = bb;
      xv = fmaf(sx[q][0], w0, xv);
      xv = fmaf(sx[q][1], w1, xv);
      xv = fmaf(sx[q][2], w2, xv);
      xv = fmaf(sx[q][3], w3, xv);
      pre[q] = (ll >= 0) ? xv : 0.f;
    }
    float av[8];
    #pragma unroll
    for (int t=0;t<8;t++){
      float a = cb;
      a = fmaf(cw0,pre[t+0],a); a = fmaf(cw1,pre[t+1],a);
      a = fmaf(cw2,pre[t+2],a); a = fmaf(cw3,pre[t+3],a);
      av[t] = a * sigmoidf_(a);
    }
    if (c < 384){
      int hh = c / 48, p = c - hh*48;
      size_t idx = (size_t)((b*8+hh)*4096 + l0)*48 + p;
      #pragma unroll
      for (int t=0;t<8;t++) xs[idx + t*48] = f2bf(av[t]);
    } else if (c < 448){
      size_t idx = (size_t)bl0*64 + (c-384);
      #pragma unroll
      for (int t=0;t<8;t++){
        ushort_t h = f2bf(av[t]);
        Bm_h[idx + t*64] = h;
        Bm_l[idx + t*64] = f2bf(av[t] - bf2f(h));
      }
    } else {
      size_t idx = (size_t)bl0*64 + (c-448);
      #pragma unroll
      for (int t=0;t<8;t++){
        ushort_t h = f2bf(av[t]);
        Cm_h[idx + t*64] = h;
        Cm_l[idx + t*64] = f2bf(av[t] - bf2f(h));
      }
    }
  }
}

// ----- phase1 (MFMA, all-single): T^T[p][n] = X^T · Bw; 6 MFMAs -----
__global__ __launch_bounds__(256, 3) void k_phase1(
    const float* __restrict__ dtbuf,
    const ushort_t* __restrict__ Bm_h,
    const ushort_t* __restrict__ xs,
    const float* __restrict__ A_log,
    ushort_t* __restrict__ T, float* __restrict__ lac){
  __shared__ __align__(16) ushort_t sBs[64*72];   // Bw^T [n][s] single
  __shared__ __align__(16) ushort_t sXs[48*72];   // X^T [p][s] single
  __shared__ float sdt[64], sla[64], sw[64];
  int tid = threadIdx.x, blk = blockIdx.x;
  int bh = blk >> 6, k = blk & 63;
  int b = bh >> 3, hh = bh & 7;
  int t0 = k*64;
  int w = tid>>6, lane = tid&63, l15 = lane&15, quad = lane>>4;

  if (tid < 64) sdt[tid] = dtbuf[(size_t)bh*4096 + t0 + tid];
  __syncthreads();
  if (tid == 0){
    float eA = __expf(A_log[hh]);
    float cum = 0.f;
    for (int i=0;i<64;i++){ cum -= sdt[i]*eA; sla[i] = cum; }
  }
  __syncthreads();
  if (tid < 64){
    sw[tid] = __expf(sla[63]-sla[tid])*sdt[tid];
    lac[(size_t)blk*64 + tid] = sla[tid];
  }
  __syncthreads();
  // ---- stage Bw^T [n][s]: B single, scale by sw, round once ----
  {
    int s2 = (tid&31)*2, ng = (tid>>5)*8;
    size_t base0 = (size_t)(b*4096+t0+s2)*64 + ng;
    ushort_t h0a[8], h1a[8];
    *(uint4*)h0a = *(const uint4*)(Bm_h + base0);
    *(uint4*)h1a = *(const uint4*)(Bm_h + base0 + 64);
    float w0 = sw[s2], w1 = sw[s2+1];
    #pragma unroll
    for (int c=0;c<8;c++){
      ushort_t h0 = f2bf(bf2f(h0a[c]) * w0);
      ushort_t h1 = f2bf(bf2f(h1a[c]) * w1);
      *(unsigned int*)&sBs[(ng+c)*72 + s2] = (unsigned int)h0 | ((unsigned int)h1<<16);
    }
  }
  // ---- stage X^T [p][s]: pure copy + pack ----
  {
    int s2 = (tid>>3)*2, p0 = (tid&7)*6;
    const ushort_t* xh0 = xs + (size_t)(bh*4096+t0+s2)*48 + p0;
    #pragma unroll
    for (int c=0;c<6;c++){
      unsigned int hv = (unsigned int)xh0[c] | ((unsigned int)xh0[48+c]<<16);
      *(unsigned int*)&sXs[(p0+c)*72 + s2] = hv;
    }
  }
  __syncthreads();
  f32x4 acc[3];
  #pragma unroll
  for (int t=0;t<3;t++) acc[t] = (f32x4)(0.f);
  #pragma unroll
  for (int ks=0;ks<2;ks++){
    int bo = (w*16+l15)*72 + ks*32 + quad*8;
    bf16x8 bbs = *(bf16x8*)&sBs[bo];
    #pragma unroll
    for (int pt=0;pt<3;pt++){
      int xo = (pt*16+l15)*72 + ks*32 + quad*8;
      bf16x8 xas = *(bf16x8*)&sXs[xo];
      acc[pt] = __builtin_amdgcn_mfma_f32_16x16x32_bf16(xas, bbs, acc[pt], 0,0,0);
    }
  }
  {
    ushort_t* dst = T + (size_t)blk*3072;
    #pragma unroll
    for (int pt=0;pt<3;pt++)
      #pragma unroll
      for (int r=0;r<4;r++)
        dst[(pt*16+quad*4+r)*64 + w*16 + l15] = f2bf(acc[pt][r]);
  }
}

// ----- phase2p: Sp[k] = sum_{j<k} W[k][j] T[j]; T bf16 in, Sp bf16 out -----
__global__ __launch_bounds__(256) void k_phase2p(
    const ushort_t* __restrict__ T, const float* __restrict__ lac,
    ushort_t* __restrict__ Sp){
  __shared__ __align__(16) float sT[64*64];
  __shared__ __align__(16) float sW[64][68];
  __shared__ float sc[64];
  int tid = threadIdx.x;
  int bh = blockIdx.x, es = blockIdx.y;
  #pragma unroll
  for (int r=0;r<2;r++){
    int idx = tid + r*256;
    int row = idx>>3, g8 = (idx&7)*8;
    ushort_t tv[8];
    *(uint4*)tv = *(const uint4*)(T + (size_t)(bh*64+row)*3072 + es*64 + g8);
    #pragma unroll
    for (int c=0;c<8;c++) sT[row*64 + g8 + c] = bf2f(tv[c]);
  }
  if (tid < 64) sc[tid] = __expf(lac[(size_t)(bh*64+tid)*64 + 63]);
  __syncthreads();
  if (tid < 64){
    int k = tid;
    float w = 1.f;
    for (int j=63; j>=0; --j){
      bool a = (j < k);
      sW[j][k] = a ? w : 0.f;
      if (a) w *= sc[j];
    }
  }
  __syncthreads();
  int k0 = (tid>>4)*4, e0 = (tid&15)*4;
  float acc[4][4];
  #pragma unroll
  for (int i=0;i<4;i++)
    #pragma unroll
    for (int j=0;j<4;j++) acc[i][j]=0.f;
  int jmax = k0+2; if (jmax > 62) jmax = 62;
  for (int j=0; j<=jmax; ++j){
    float wv[4], tv[4];
    *(float4*)wv = *(float4*)&sW[j][k0];
    *(float4*)tv = *(float4*)&sT[j*64 + e0];
    #pragma unroll
    for (int i=0;i<4;i++)
      #pragma unroll
      for (int e=0;e<4;e++) acc[i][e] = fmaf(wv[i], tv[e], acc[i][e]);
  }
  #pragma unroll
  for (int i=0;i<4;i++){
    ushort4 h4;
    ushort_t* hp = (ushort_t*)&h4;
    #pragma unroll
    for (int e=0;e<4;e++) hp[e] = f2bf(acc[i][e]);
    *(ushort4*)(Sp + (size_t)(bh*64+k0+i)*3072 + es*64 + e0) = h4;
  }
}

// ----- phase3 (MFMA) + fused gate: GM 3-term; intra/carry single-term -----
__global__ __launch_bounds__(256, 3) void k_phase3(
    const float* __restrict__ dtbuf, const float* __restrict__ lac,
    const ushort_t* __restrict__ Bm_h, const ushort_t* __restrict__ Bm_l,
    const ushort_t* __restrict__ Cm_h, const ushort_t* __restrict__ Cm_l,
    const ushort_t* __restrict__ xs,
    const ushort_t* __restrict__ Sp, const float* __restrict__ Dparam,
    const float* __restrict__ xg, const float* __restrict__ Weff,
    const float* __restrict__ beff,
    ushort_t* __restrict__ g16, float* __restrict__ ssum){
  __shared__ __align__(16) ushort_t sCh[64*72], sCl[64*72];   // C[i][n]
  __shared__ __align__(16) ushort_t sBh[64*72], sBl[64*72];   // B[s][n] -> GM[i][s]
  __shared__ __align__(16) ushort_t sXs[48*72];               // X^T[p][s] single
  __shared__ float sla[64], sdt[64];
  int tid = threadIdx.x, blk = blockIdx.x;
  int bh = blk>>6, k = blk&63, b = bh>>3, hh = bh&7, t0 = k*64;
  int w = tid>>6, lane = tid&63, l15 = lane&15, quad = lane>>4;

  if (tid < 64){
    sdt[tid] = dtbuf[(size_t)bh*4096 + t0 + tid];
    sla[tid] = lac[(size_t)blk*64 + tid];
  }
  // ---- stage C, B: pure 16B copies ----
  {
    int row = tid>>2, ng = (tid&3)*16;
    size_t gb = (size_t)(b*4096+t0+row)*64 + ng;
    int o = row*72 + ng;
    *(uint4*)&sCh[o]   = *(const uint4*)(Cm_h + gb);
    *(uint4*)&sCh[o+8] = *(const uint4*)(Cm_h + gb + 8);
    *(uint4*)&sCl[o]   = *(const uint4*)(Cm_l + gb);
    *(uint4*)&sCl[o+8] = *(const uint4*)(Cm_l + gb + 8);
    *(uint4*)&sBh[o]   = *(const uint4*)(Bm_h + gb);
    *(uint4*)&sBh[o+8] = *(const uint4*)(Bm_h + gb + 8);
    *(uint4*)&sBl[o]   = *(const uint4*)(Bm_l + gb);
    *(uint4*)&sBl[o+8] = *(const uint4*)(Bm_l + gb + 8);
  }
  // ---- stage X^T single: copy + pack ----
  {
    int s2 = (tid>>3)*2, p0 = (tid&7)*6;
    const ushort_t* xh0 = xs + (size_t)(bh*4096+t0+s2)*48 + p0;
    #pragma unroll
    for (int c=0;c<6;c++){
      unsigned int hv = (unsigned int)xh0[c] | ((unsigned int)xh0[48+c]<<16);
      *(unsigned int*)&sXs[(p0+c)*72 + s2] = hv;
    }
  }
  __syncthreads();

  // ---- GM mfma: wave w owns i-band w, s-tiles 0..w (3-term split) ----
  f32x4 gacc[4];
  #pragma unroll
  for (int t=0;t<4;t++) gacc[t] = (f32x4)(0.f);
  {
    bf16x8 cah[2], cal[2];
    #pragma unroll
    for (int ks=0;ks<2;ks++){
      int ao = (w*16+l15)*72 + ks*32 + quad*8;
      cah[ks] = *(bf16x8*)&sCh[ao];
      cal[ks] = *(bf16x8*)&sCl[ao];
    }
    for (int bs=0; bs<=w; ++bs){
      #pragma unroll
      for (int ks=0;ks<2;ks++){
        int bo = (bs*16+l15)*72 + ks*32 + quad*8;
        bf16x8 bhf = *(bf16x8*)&sBh[bo];
        bf16x8 blf = *(bf16x8*)&sBl[bo];
        gacc[bs] = __builtin_amdgcn_mfma_f32_16x16x32_bf16(cah[ks], bhf, gacc[bs], 0,0,0);
        gacc[bs] = __builtin_amdgcn_mfma_f32_16x16x32_bf16(cah[ks], blf, gacc[bs], 0,0,0);
        gacc[bs] = __builtin_amdgcn_mfma_f32_16x16x32_bf16(cal[ks], bhf, gacc[bs], 0,0,0);
      }
    }
  }
  __syncthreads();   // sB reads done -> safe to overwrite with GM

  // ---- scale/mask, write GM single bf16 into sBh; zero needed tiles ----
  for (int bs=0; bs<=w; ++bs){
    #pragma unroll
    for (int r=0;r<4;r++){
      int i = w*16 + quad*4 + r;
      int s = bs*16 + l15;
      float v = 0.f;
      if (s <= i) v = gacc[bs][r] * __expf(sla[i]-sla[s]) * sdt[s];
      sBh[i*72+s] = f2bf(v);
    }
  }
  if (w==0){
    #pragma unroll
    for (int r=0;r<4;r++) sBh[(quad*4+r)*72 + 16+l15] = 0;
  }
  if (w==2){
    #pragma unroll
    for (int r=0;r<4;r++) sBh[(32+quad*4+r)*72 + 48+l15] = 0;
  }
  __syncthreads();

  // ---- Sp fragments direct (single bf16, [p][n] layout) ----
  bf16x8 pah[3][2];
  {
    const ushort_t* sph = Sp + (size_t)blk*3072;
    #pragma unroll
    for (int pt=0;pt<3;pt++)
      #pragma unroll
      for (int ks=0;ks<2;ks++)
        pah[pt][ks] = *(const bf16x8*)(sph + (size_t)(pt*16+l15)*64 + ks*32 + quad*8);
  }

  // ---- O = X^T·GM^T (intra; both single -> 1 MFMA/tile) ----
  f32x4 accI[3], accA[3];
  #pragma unroll
  for (int t=0;t<3;t++){ accI[t] = (f32x4)(0.f); accA[t] = (f32x4)(0.f); }
  int nks = (w>=2) ? 2 : 1;
  for (int ks=0; ks<nks; ++ks){
    int go = (w*16+l15)*72 + ks*32 + quad*8;
    bf16x8 gbh = *(bf16x8*)&sBh[go];
    #pragma unroll
    for (int pt=0;pt<3;pt++){
      bf16x8 xas = *(bf16x8*)&sXs[(pt*16+l15)*72 + ks*32 + quad*8];
      accI[pt] = __builtin_amdgcn_mfma_f32_16x16x32_bf16(xas, gbh, accI[pt], 0,0,0);
    }
  }
  // ---- + Sp^T·C^T (carry; Sp single x C_hi -> 1 MFMA/tile) ----
  #pragma unroll
  for (int ks=0; ks<2; ++ks){
    int co = (w*16+l15)*72 + ks*32 + quad*8;
    bf16x8 cbh = *(bf16x8*)&sCh[co];
    #pragma unroll
    for (int pt=0;pt<3;pt++)
      accA[pt] = __builtin_amdgcn_mfma_f32_16x16x32_bf16(pah[pt][ks], cbh, accA[pt], 0,0,0);
  }
  // ---- epilogue: y = accI + e^la*accA + D*x; g = y*silu(z); ssum += g^2 ----
  {
    int i = w*16 + l15;
    int tok = b*4096 + t0 + i;
    float eli = __expf(sla[i]);
    float Dh = Dparam[hh];
    float4 xv = *(const float4*)(xg + (size_t)tok*4);
    ushort_t* gbase = g16 + (size_t)tok*384 + hh*48;
    float ssq = 0.f;
    #pragma unroll
    for (int pt=0;pt<3;pt++)
      #pragma unroll
      for (int r=0;r<4;r++){
        int p = pt*16 + quad*4 + r;
        float xf = bf2f(sXs[p*72 + i]);
        float yv = accI[pt][r] + eli*accA[pt][r] + Dh*xf;
        int e = hh*48 + p;
        float zv = beff[e];
        zv = fmaf(xv.x, Weff[e], zv);
        zv = fmaf(xv.y, Weff[904+e], zv);
        zv = fmaf(xv.z, Weff[1808+e], zv);
        zv = fmaf(xv.w, Weff[2712+e], zv);
        float gg = yv * (zv * sigmoidf_(zv));
        gbase[p] = f2bf(gg);
        ssq += gg*gg;
      }
    ssq += __shfl_xor(ssq, 16);
    ssq += __shfl_xor(ssq, 32);
    if (quad == 0) atomicAdd(&ssum[tok], ssq);
  }
}

// ----- mlp2: 32 tokens/block (512 blocks), 1 token/thread; rms inline -----
__global__ __launch_bounds__(256) void k_mlp2(
    const ushort_t* __restrict__ g16, const float* __restrict__ ssum,
    const float* __restrict__ Weff2, const float* __restrict__ b1,
    const float* __restrict__ W2, const float* __restrict__ b2,
    float* __restrict__ macc){
  __shared__ __align__(16) float sW[384][32];
  __shared__ __align__(16) float sm1[32][33];
  __shared__ __align__(16) float sW2[32][32];
  __shared__ __align__(16) float sm2[32][33];
  int tid = threadIdx.x;
  int tok0 = blockIdx.x*32;
  int b = tok0 >> 12;
  #pragma unroll
  for (int r=0;r<12;r++){
    int idx = tid + r*256;
    int row = idx>>3, c4 = (idx&7)*4;
    *(float4*)&sW[row][c4] = *(const float4*)(Weff2 + (size_t)idx*4);
  }
  {
    int row = tid>>3, c4 = (tid&7)*4;
    *(float4*)&sW2[row][c4] = *(const float4*)(W2 + row*32 + c4);
  }
  __syncthreads();
  {
    int tk = tid>>3, j0 = (tid&7)*4;
    float rms0 = rsqrtf(ssum[tok0+tk]*(1.f/384.f) + 1e-5f);
    float a0[4];
    #pragma unroll
    for (int j=0;j<4;j++) a0[j] = b1[j0+j];
    const ushort_t* y0 = g16 + (size_t)(tok0+tk)*384;
    for (int k8=0;k8<48;k8++){
      ushort_t ua[8];
      *(uint4*)ua = *(const uint4*)(y0 + k8*8);
      #pragma unroll
      for (int c=0;c<8;c++){
        float va = bf2f(ua[c])*rms0;
        float w[4]; *(float4*)w = *(float4*)&sW[k8*8+c][j0];
        #pragma unroll
        for (int j=0;j<4;j++) a0[j] = fmaf(va, w[j], a0[j]);
      }
    }
    #pragma unroll
    for (int j=0;j<4;j++) sm1[tk][j0+j] = fmaxf(a0[j], 0.f);
  }
  __syncthreads();
  {
    int tk = tid>>3, j0 = (tid&7)*4;
    float a0[4];
    #pragma unroll
    for (int j=0;j<4;j++) a0[j] = b2[j0+j];
    #pragma unroll
    for (int kk=0;kk<32;kk++){
      float va = sm1[tk][kk];
      float w[4]; *(float4*)w = *(float4*)&sW2[kk][j0];
      #pragma unroll
      for (int j=0;j<4;j++) a0[j] = fmaf(va, w[j], a0[j]);
    }
    #pragma unroll
    for (int j=0;j<4;j++) sm2[tk][j0+j] = fmaxf(a0[j], 0.f);
  }
  __syncthreads();
  if (tid < 32){
    float t = 0.f;
    #pragma unroll
    for (int tok=0;tok<32;tok++) t += sm2[tok][tid];
    atomicAdd(&macc[b*32 + tid], t);
  }
}

// ----- final: angle[b] = mean_m @ Wo + bo -----
__global__ void k_final(const float* __restrict__ macc, const float* __restrict__ Wo,
                        const float* __restrict__ bo, float* __restrict__ out){
  int tid = threadIdx.x;
  if (tid < 4){
    float acc = bo[0];
    #pragma unroll
    for (int j=0;j<32;j++) acc = fmaf(macc[tid*32+j]*(1.f/4096.f), Wo[j], acc);
    out[tid] = acc;
  }
}

// ---------------------------------------------------------------------------
extern "C" void kernel_launch(void* const* d_in, const int* in_sizes, int n_in,
                              void* d_out, int out_size, void* d_ws, size_t ws_size,
                              hipStream_t stream){
  const float* x      = (const float*)d_in[0];
  const float* Wfc    = (const float*)d_in[1];
  const float* bfc    = (const float*)d_in[2];
  const float* W_in   = (const float*)d_in[3];
  const float* conv_w = (const float*)d_in[4];
  const float* conv_b = (const float*)d_in[5];
  const float* dt_bias= (const float*)d_in[6];
  const float* A_log  = (const float*)d_in[7];
  const float* Dparam = (const float*)d_in[8];
  const float* norm_w = (const float*)d_in[9];
  const float* W_out  = (const float*)d_in[10];
  const float* W1     = (const float*)d_in[11];
  const float* b1     = (const float*)d_in[12];
  const float* W2     = (const float*)d_in[13];
  const float* b2     = (const float*)d_in[14];
  const float* Wo     = (const float*)d_in[15];
  const float* bo     = (const float*)d_in[16];
  float* ws  = (float*)d_ws;
  float* out = (float*)d_out;

  float* Weff  = ws + OFF_W;
  float* beff  = ws + OFF_W + 4096;
  float* Weff2 = ws + OFF_W + 8192;
  float* ssum  = ws + OFF_Z;            // 16384 fp32
  ushort_t* Tb   = (ushort_t*)(ws + OFF_T);
  ushort_t* xsb  = (ushort_t*)(ws + OFF_XS);
  ushort_t* Bm_h = (ushort_t*)(ws + OFF_BM);
  ushort_t* Bm_l = Bm_h + 1048576u;     // 16384*64
  ushort_t* Cm_h = (ushort_t*)(ws + OFF_CM);
  ushort_t* Cm_l = Cm_h + 1048576u;
  float* dtb   = ws + OFF_DT;
  float* lacb  = ws + OFF_LAC;
  ushort_t* Spb  = (ushort_t*)(ws + OFF_SP);
  ushort_t* g16 = (ushort_t*)(ws + OFF_Y);
  float* macc  = ws + OFF_MACC;

  k_prep<<<dim3(116), dim3(256), 0, stream>>>(Wfc, bfc, W_in, W_out, W1, norm_w,
                                              Weff, beff, Weff2, macc, ssum);
  k_ipc<<<dim3(BL/8), dim3(256), 0, stream>>>(x, Weff, beff, conv_w, conv_b,
                                              dt_bias, xsb, Bm_h, Bm_l,
                                              Cm_h, Cm_l, dtb);
  k_phase1<<<dim3(BH*NC), dim3(256), 0, stream>>>(dtb, Bm_h, xsb, A_log, Tb, lacb);
  k_phase2p<<<dim3(BH,48), dim3(256), 0, stream>>>(Tb, lacb, Spb);
  k_phase3<<<dim3(BH*NC), dim3(256), 0, stream>>>(dtb, lacb, Bm_h, Bm_l,
                                                  Cm_h, Cm_l, xsb,
                                                  Spb, Dparam, x, Weff, beff,
                                                  g16, ssum);
  k_mlp2<<<dim3(BL/32), dim3(256), 0, stream>>>(g16, ssum, Weff2, b1, W2, b2, macc);
  k_final<<<dim3(1), dim3(64), 0, stream>>>(macc, Wo, bo, out);
}